// Round 1
// baseline (1911.594 us; speedup 1.0000x reference)
//
#include <hip/hip_runtime.h>

#define S_LEN 2048
#define DKV   64
#define NEG_BIG -1000000000.0f
#define CTX_ELEMS (4u*16u*2048u*64u)   // 8,388,608

typedef _Float16 f16x8 __attribute__((ext_vector_type(8)));
typedef float    f32x4 __attribute__((ext_vector_type(4)));

// LDS layout (bytes):
//   [0, 86016)       : per-wave staging, 8 waves * 10752
//                        VT  [64][56] f16 = 7168  (V^T tile, chunk of 32 k)
//                        Pt  [32][56] f16 = 3584  (P tile for A-operand reads)
//                      aliased afterwards by ctxbuf [8][32][64] f32 = 65536
//   [86016, 87040)   : redA [8][32] f32  (row max)
//   [87040, 88064)   : redB [8][32] f32  (row sum)
//   [88064, 88192)   : rowinv [32] f32
#define SMEM_BYTES 88192

__global__ void mask_probe_kernel(const unsigned int* __restrict__ m,
                                  unsigned int* __restrict__ flag)
{
    // Scan first 16 MB (= whole buffer if mask is bytes, first quarter if int32).
    // int32 {0,1} mask: every word is 0 or 1.  byte mask: words pack 4 bools,
    // values like 0x00010001 appear with prob 7/8 per word -> certain detection.
    unsigned int bad = 0u;
    for (int i = blockIdx.x * blockDim.x + threadIdx.x; i < 4194304;
         i += gridDim.x * blockDim.x) {
        if (m[i] > 1u) bad = 1u;
    }
    if (bad) atomicOr(flag, 1u);
}

__global__ __launch_bounds__(512, 2)
void sdpa_kernel(const float* __restrict__ Qg, const float* __restrict__ Kg,
                 const float* __restrict__ Vg, const unsigned char* __restrict__ Mg,
                 const unsigned int* __restrict__ flag, float* __restrict__ out)
{
    __shared__ __align__(16) char smem[SMEM_BYTES];

    const int tid  = threadIdx.x;
    const int w    = tid >> 6;        // wave 0..7
    const int lane = tid & 63;
    const int g    = lane >> 4;       // quarter-wave group 0..3
    const int c16  = lane & 15;
    const int qb   = blockIdx.x & 63; // q-block within (b,h)
    const int bh   = blockIdx.x >> 6; // 0..63
    const int b    = bh >> 4;
    const int q0   = qb * 32;
    const int col0 = w * 256;         // this wave's k-column slice
    // mask element stride: int32 -> byte offset = idx<<2 (low byte holds 0/1),
    // raw bytes -> idx<<0.
    const int mshift = (flag[0] != 0u) ? 0 : 2;

    // ---------------- Q fragments (A-operand): row = c16, k = g*8+i ----------
    f16x8 xq[2][2];
    const float* Qb = Qg + ((size_t)bh * S_LEN + q0) * DKV;
#pragma unroll
    for (int qt = 0; qt < 2; ++qt) {
#pragma unroll
        for (int c = 0; c < 2; ++c) {
            const float* p = Qb + (qt * 16 + c16) * DKV + c * 32 + g * 8;
            f32x4 a = *(const f32x4*)p;
            f32x4 bb = *(const f32x4*)(p + 4);
            f16x8 xf;
#pragma unroll
            for (int j = 0; j < 4; ++j) {
                xf[j]     = (_Float16)a[j];
                xf[4 + j] = (_Float16)bb[j];
            }
            xq[qt][c] = xf;
        }
    }

    // ---------------- QK^T: acc[qt][T] = 16x16 tile, cols col0+T*16 ----------
    const f32x4 z4 = {0.f, 0.f, 0.f, 0.f};
    f32x4 acc[2][16];
#pragma unroll
    for (int qt = 0; qt < 2; ++qt)
#pragma unroll
        for (int T = 0; T < 16; ++T) acc[qt][T] = z4;

    const float* Kb = Kg + ((size_t)bh * S_LEN + col0) * DKV;
#pragma unroll
    for (int T = 0; T < 16; ++T) {
        f16x8 y[2];
#pragma unroll
        for (int c = 0; c < 2; ++c) {
            const float* p = Kb + (T * 16 + c16) * DKV + c * 32 + g * 8;
            f32x4 a = *(const f32x4*)p;
            f32x4 bb = *(const f32x4*)(p + 4);
            f16x8 yf;
#pragma unroll
            for (int j = 0; j < 4; ++j) {
                yf[j]     = (_Float16)a[j];
                yf[4 + j] = (_Float16)bb[j];
            }
            y[c] = yf;
        }
        acc[0][T] = __builtin_amdgcn_mfma_f32_16x16x32_f16(xq[0][0], y[0], acc[0][T], 0, 0, 0);
        acc[0][T] = __builtin_amdgcn_mfma_f32_16x16x32_f16(xq[0][1], y[1], acc[0][T], 0, 0, 0);
        acc[1][T] = __builtin_amdgcn_mfma_f32_16x16x32_f16(xq[1][0], y[0], acc[1][T], 0, 0, 0);
        acc[1][T] = __builtin_amdgcn_mfma_f32_16x16x32_f16(xq[1][1], y[1], acc[1][T], 0, 0, 0);
    }

    float* redA   = (float*)(smem + 86016);
    float* redB   = (float*)(smem + 87040);
    float* rowinv = (float*)(smem + 88064);

    // ---------------- mask + scale + row max --------------------------------
    // D layout: score[q0 + qt*16 + g*4 + r][col0 + T*16 + c16] = acc[qt][T][r]
    float rmax[2][4];
#pragma unroll
    for (int qt = 0; qt < 2; ++qt) {
#pragma unroll
        for (int r = 0; r < 4; ++r) {
            const int qrow = q0 + qt * 16 + g * 4 + r;
            const size_t rowbase = ((size_t)b * S_LEN + qrow) * (size_t)S_LEN;
            const unsigned char* mp = Mg + ((rowbase + col0 + c16) << mshift);
            float mx = -3.4e38f;
#pragma unroll
            for (int T = 0; T < 16; ++T) {
                unsigned char mv = mp[(size_t)(T * 16) << mshift];
                float s = mv ? NEG_BIG : acc[qt][T][r] * 0.125f;
                acc[qt][T][r] = s;
                mx = fmaxf(mx, s);
            }
#pragma unroll
            for (int x = 1; x < 16; x <<= 1) mx = fmaxf(mx, __shfl_xor(mx, x));
            rmax[qt][r] = mx;
        }
    }
    if (c16 == 0) {
#pragma unroll
        for (int qt = 0; qt < 2; ++qt)
#pragma unroll
            for (int r = 0; r < 4; ++r)
                redA[w * 32 + qt * 16 + g * 4 + r] = rmax[qt][r];
    }
    __syncthreads();
#pragma unroll
    for (int qt = 0; qt < 2; ++qt)
#pragma unroll
        for (int r = 0; r < 4; ++r) {
            float mx = -3.4e38f;
#pragma unroll
            for (int w2 = 0; w2 < 8; ++w2)
                mx = fmaxf(mx, redA[w2 * 32 + qt * 16 + g * 4 + r]);
            rmax[qt][r] = mx;
        }

    // ---------------- exp + row sum -----------------------------------------
    float rsum[2][4];
#pragma unroll
    for (int qt = 0; qt < 2; ++qt)
#pragma unroll
        for (int r = 0; r < 4; ++r) {
            const float m = rmax[qt][r];
            float ssum = 0.f;
#pragma unroll
            for (int T = 0; T < 16; ++T) {
                float e = __expf(acc[qt][T][r] - m);
                acc[qt][T][r] = e;   // unnormalized
                ssum += e;
            }
#pragma unroll
            for (int x = 1; x < 16; x <<= 1) ssum += __shfl_xor(ssum, x);
            rsum[qt][r] = ssum;
        }
    if (c16 == 0) {
#pragma unroll
        for (int qt = 0; qt < 2; ++qt)
#pragma unroll
            for (int r = 0; r < 4; ++r)
                redB[w * 32 + qt * 16 + g * 4 + r] = rsum[qt][r];
    }
    __syncthreads();
    float rinv[2][4];
#pragma unroll
    for (int qt = 0; qt < 2; ++qt)
#pragma unroll
        for (int r = 0; r < 4; ++r) {
            float s = 0.f;
#pragma unroll
            for (int w2 = 0; w2 < 8; ++w2)
                s += redB[w2 * 32 + qt * 16 + g * 4 + r];
            rinv[qt][r] = 1.0f / s;
        }
    if (w == 0 && c16 == 0) {
#pragma unroll
        for (int qt = 0; qt < 2; ++qt)
#pragma unroll
            for (int r = 0; r < 4; ++r)
                rowinv[qt * 16 + g * 4 + r] = rinv[qt][r];
    }

    // ---------------- store attn_score (normalized) -------------------------
    float* outS = out + (size_t)CTX_ELEMS;
#pragma unroll
    for (int qt = 0; qt < 2; ++qt)
#pragma unroll
        for (int r = 0; r < 4; ++r) {
            const int qrow = q0 + qt * 16 + g * 4 + r;
            float* op = outS + ((size_t)bh * S_LEN + qrow) * S_LEN + col0 + c16;
            const float riv = rinv[qt][r];
#pragma unroll
            for (int T = 0; T < 16; ++T) op[T * 16] = acc[qt][T][r] * riv;
        }

    // ---------------- PV: ctx[qt][dt] over this wave's k-slice --------------
    _Float16* VT = (_Float16*)(smem + w * 10752);          // [64][56] (d, k)
    _Float16* Pt = (_Float16*)(smem + w * 10752 + 7168);   // [32][56] (q, k)
    f32x4 ctx[2][4];
#pragma unroll
    for (int qt = 0; qt < 2; ++qt)
#pragma unroll
        for (int dt = 0; dt < 4; ++dt) ctx[qt][dt] = z4;

    const float* Vb = Vg + ((size_t)bh * S_LEN + col0) * DKV;
#pragma unroll
    for (int ch = 0; ch < 8; ++ch) {          // 32 k-cols per chunk
        // P tile -> LDS (transpose for A-operand)
#pragma unroll
        for (int qt = 0; qt < 2; ++qt)
#pragma unroll
            for (int Tl = 0; Tl < 2; ++Tl)
#pragma unroll
                for (int r = 0; r < 4; ++r)
                    Pt[(qt * 16 + g * 4 + r) * 56 + Tl * 16 + c16] =
                        (_Float16)acc[qt][2 * ch + Tl][r];
        // V chunk -> LDS transposed as f16
#pragma unroll
        for (int s = 0; s < 4; ++s) {
            const float* p = Vb + (ch * 32 + s * 8 + (lane >> 3)) * DKV + (lane & 7) * 8;
            f32x4 a = *(const f32x4*)p;
            f32x4 bb = *(const f32x4*)(p + 4);
            const int kloc = s * 8 + (lane >> 3);
            const int d0 = (lane & 7) * 8;
#pragma unroll
            for (int j = 0; j < 4; ++j) {
                VT[(d0 + j) * 56 + kloc]     = (_Float16)a[j];
                VT[(d0 + 4 + j) * 56 + kloc] = (_Float16)bb[j];
            }
        }
        __syncthreads();
        f16x8 xp[2], yv[4];
#pragma unroll
        for (int qt = 0; qt < 2; ++qt)
            xp[qt] = *(const f16x8*)&Pt[(qt * 16 + c16) * 56 + g * 8];
#pragma unroll
        for (int dt = 0; dt < 4; ++dt)
            yv[dt] = *(const f16x8*)&VT[(dt * 16 + c16) * 56 + g * 8];
#pragma unroll
        for (int qt = 0; qt < 2; ++qt)
#pragma unroll
            for (int dt = 0; dt < 4; ++dt)
                ctx[qt][dt] = __builtin_amdgcn_mfma_f32_16x16x32_f16(
                    xp[qt], yv[dt], ctx[qt][dt], 0, 0, 0);
        __syncthreads();
    }

    // ---------------- cross-wave context reduction + write -------------------
    float* ctxbuf = (float*)smem;   // [8][32][64], aliases VT/Pt (barrier above)
#pragma unroll
    for (int qt = 0; qt < 2; ++qt)
#pragma unroll
        for (int dt = 0; dt < 4; ++dt)
#pragma unroll
            for (int r = 0; r < 4; ++r)
                ctxbuf[(w * 32 + qt * 16 + g * 4 + r) * 64 + dt * 16 + c16] =
                    ctx[qt][dt][r];
    __syncthreads();
#pragma unroll
    for (int rr = 0; rr < 4; ++rr) {
        const int row = w * 4 + rr;
        float s = 0.f;
#pragma unroll
        for (int w2 = 0; w2 < 8; ++w2)
            s += ctxbuf[(w2 * 32 + row) * 64 + lane];
        s *= rowinv[row];
        out[((size_t)bh * S_LEN + q0 + row) * DKV + lane] = s;
    }
}

extern "C" void kernel_launch(void* const* d_in, const int* in_sizes, int n_in,
                              void* d_out, int out_size, void* d_ws, size_t ws_size,
                              hipStream_t stream)
{
    const float* Q = (const float*)d_in[0];
    const float* K = (const float*)d_in[1];
    const float* V = (const float*)d_in[2];
    const unsigned char* M = (const unsigned char*)d_in[3];
    float* out = (float*)d_out;
    unsigned int* flag = (unsigned int*)d_ws;

    hipMemsetAsync(flag, 0, sizeof(unsigned int), stream);
    mask_probe_kernel<<<dim3(256), dim3(256), 0, stream>>>(
        (const unsigned int*)M, flag);
    sdpa_kernel<<<dim3(4096), dim3(512), 0, stream>>>(Q, K, V, M, flag, out);
}